// Round 9
// baseline (217.125 us; speedup 1.0000x reference)
//
#include <hip/hip_runtime.h>
#include <hip/hip_bf16.h>

// Problem constants
#define BATCH 8
#define CCH   256
#define NPOS  4096
#define CQK   32
#define LOG2E 1.4426950408889634f

typedef __attribute__((ext_vector_type(8))) short short8;   // 8 bf16 = 4 VGPRs (MFMA A/B frag)
typedef __attribute__((ext_vector_type(4))) float f32x4;    // MFMA C/D frag

__device__ inline unsigned short f2b(float f) {
    __hip_bfloat16 h = __float2bfloat16(f);
    return *reinterpret_cast<unsigned short*>(&h);
}

// ---------------------------------------------------------------------------
// Fragment-block swizzled layouts.  A 512-short block holds one 16x32 MFMA
// operand tile; lane (q=quad, ln) reads short8 at block*512 + (q*16+ln)*8.
//   qb/kb: qk_addr  — [b][n>>4][c>>3][n&15][c&7]           (c < 32)
//   vb:     v_addr  — [b][j>>5][c>>4][(j>>3)&3][c&15][j&7]
//   wsw:    wsw_addr — og-unit = 16 rows x 256 c; og: q=0..1,k=2..3,v=4..19,f=20..35
// ---------------------------------------------------------------------------
__device__ inline size_t qk_addr(int b, int n, int c) {
    return ((((size_t)b * 256 + (n >> 4)) * 4 + (c >> 3)) * 16 + (n & 15)) * 8 + (c & 7);
}
__device__ inline size_t v_addr(int b, int c, int j) {
    return (((((size_t)b * 128 + (j >> 5)) * 16 + (c >> 4)) * 4 + ((j >> 3) & 3)) * 16 + (c & 15)) * 8 + (j & 7);
}
__device__ inline size_t wsw_addr(int og, int c, int ol) {
    return ((size_t)(og * 8 + (c >> 5))) * 512 + (((c >> 3) & 3) * 16 + ol) * 8 + (c & 7);
}

// ---------------------------------------------------------------------------
// Kernel 0: prep_w — weights fp32 -> wsw bf16 fragment layout.
// Wk (og 2..3) pre-scaled by log2(e): attn computes exp(S) as exp2(S')
// with S' = (log2e*K)^T Q — one v_exp_f32, no v_mul.
// ---------------------------------------------------------------------------
__global__ __launch_bounds__(256, 4)
void prep_w_kernel(const float* __restrict__ Wq, const float* __restrict__ Wk,
                   const float* __restrict__ Wv, const float* __restrict__ Wf,
                   unsigned short* __restrict__ wsw)
{
    const int og = blockIdx.x;           // 0..35
    const int t  = threadIdx.x;
    const float* src; int orow; float scl = 1.f;
    if (og < 2)       { src = Wq; orow = og * 16; }
    else if (og < 4)  { src = Wk; orow = (og - 2) * 16; scl = LOG2E; }
    else if (og < 20) { src = Wv; orow = (og - 4) * 16; }
    else              { src = Wf; orow = (og - 20) * 16; }
    #pragma unroll
    for (int e = 0; e < 16; ++e) {
        int idx = t + e * 256;
        int ol = idx >> 8, c = idx & 255;
        wsw[wsw_addr(og, c, ol)] = f2b(src[(orow + ol) * 256 + c] * scl);
    }
}

// ---------------------------------------------------------------------------
// Kernel 1: fused transpose + QKV projection (R4/R8 structure, unchanged —
// part of the best-measured non-attn configuration).
// ---------------------------------------------------------------------------
__global__ __launch_bounds__(512, 2)
void qkv_kernel(const float* __restrict__ x,
                const unsigned short* __restrict__ wsw,
                const float* __restrict__ bq, const float* __restrict__ bk,
                const float* __restrict__ bv,
                unsigned short* __restrict__ qb, unsigned short* __restrict__ kb,
                unsigned short* __restrict__ vb)
{
    __shared__ __align__(16) unsigned short xl[64 * 280];   // [n][c pad 280] = 35840 B

    const int nt   = blockIdx.x;          // 64 position tiles
    const int b    = blockIdx.y;
    const int t    = threadIdx.x;         // 0..511
    const int w    = t >> 6;              // 0..7
    const int lane = t & 63;
    const int q    = lane >> 4;
    const int ln   = lane & 15;
    const int lofs = (q * 16 + ln) * 8;
    const int wq   = w & 3;               // role: 0-1 q, 2-3 k (+ v og chunk)
    const int ith  = w >> 2;              // it-half

    // ---- stage x tile [256c x 64n] -> bf16 LDS transposed [n][c] ----
    {
        const int c  = t & 255;
        const int nb = (t >> 8) * 4;
        const float* xb = x + ((size_t)(b * 256 + c)) * 4096 + nt * 64;
        #pragma unroll
        for (int e = 0; e < 8; ++e) {
            const int n = nb + e * 8;
            float4 v = *(const float4*)(xb + n);
            xl[(n + 0) * 280 + c] = f2b(v.x);
            xl[(n + 1) * 280 + c] = f2b(v.y);
            xl[(n + 2) * 280 + c] = f2b(v.z);
            xl[(n + 3) * 280 + c] = f2b(v.w);
        }
    }
    __syncthreads();

    // ---- q/k weight fragments (og = wq) + bias (k side scaled by log2e) ----
    short8 wqk[8];
    #pragma unroll
    for (int kk = 0; kk < 8; ++kk)
        wqk[kk] = *(const short8*)(wsw + (size_t)(wq * 8 + kk) * 512 + lofs);
    const float* bias = (wq < 2) ? bq : bk;
    const float ksc = (wq < 2) ? 1.f : LOG2E;
    const int cb16 = (wq & 1) * 16;
    const float b0 = bias[cb16 + q * 4 + 0] * ksc;
    const float b1 = bias[cb16 + q * 4 + 1] * ksc;
    const float b2 = bias[cb16 + q * 4 + 2] * ksc;
    const float b3 = bias[cb16 + q * 4 + 3] * ksc;
    unsigned short* dst = (wq < 2) ? qb : kb;

    #pragma unroll
    for (int itl = 0; itl < 2; ++itl) {
        const int it = ith * 2 + itl;
        short8 xf[8];
        #pragma unroll
        for (int kk = 0; kk < 8; ++kk)
            xf[kk] = *(const short8*)&xl[(it * 16 + ln) * 280 + kk * 32 + q * 8];

        // ---- q/k: D[o-rows][n-cols] ----
        {
            f32x4 acc = {b0, b1, b2, b3};
            #pragma unroll
            for (int kk = 0; kk < 8; ++kk)
                acc = __builtin_amdgcn_mfma_f32_16x16x32_bf16(wqk[kk], xf[kk], acc, 0, 0, 0);
            ushort4 s = {f2b(acc[0]), f2b(acc[1]), f2b(acc[2]), f2b(acc[3])};
            *(ushort4*)(dst + qk_addr(b, nt * 64 + it * 16 + ln, cb16 + q * 4)) = s;
        }

        // ---- v: D[j-rows][c-cols], o-chunk wq*64 ----
        #pragma unroll
        for (int oq = 0; oq < 4; ++oq) {
            const int c  = wq * 64 + oq * 16 + ln;
            const float bb = bv[c];
            f32x4 acc = {bb, bb, bb, bb};
            const int og = 4 + wq * 4 + oq;
            #pragma unroll
            for (int kk = 0; kk < 8; ++kk) {
                short8 bfr = *(const short8*)(wsw + (size_t)(og * 8 + kk) * 512 + lofs);
                acc = __builtin_amdgcn_mfma_f32_16x16x32_bf16(xf[kk], bfr, acc, 0, 0, 0);
            }
            ushort4 s = {f2b(acc[0]), f2b(acc[1]), f2b(acc[2]), f2b(acc[3])};
            *(ushort4*)(vb + v_addr(b, c, nt * 64 + it * 16 + q * 4)) = s;
        }
    }
}

// ---------------------------------------------------------------------------
// Kernel 2: fused flash attention + output projection — R9 = REVERT to the
// best-measured R2 structure (103.4 µs): S = mfma(Q,K) non-swapped,
// P buffer [2][64][72] with scalar P-writes, accl[4] + width-16 shfl reduce,
// single-depth next-iter K/V register prefetch, one barrier/iter.
// Only delta vs R2: exp2f (K pre-scaled by log2e) — 16 fewer v_mul/iter.
// R5's S^T+swizzle (−conflicts, +7µs) and R8's ping-pong (+7µs) both reverted.
// ---------------------------------------------------------------------------
__global__ __launch_bounds__(256, 2)
void attn_kernel(const unsigned short* __restrict__ qb,
                 const unsigned short* __restrict__ kb,
                 const unsigned short* __restrict__ vb,
                 const unsigned short* __restrict__ wsw,
                 const float* __restrict__ bfb, float* __restrict__ out)
{
    // shbuf aliases: main loop P tiles [2][64][72] (9216 shorts),
    //                epilogue O_n      [64][264]   (16896 shorts)
    __shared__ __align__(16) unsigned short shbuf[64 * 264];
    __shared__ float lred[64];

    const int bid  = blockIdx.x;
    const int b    = bid & 7;                    // XCD swizzle
    const int i0   = (bid >> 3) * 64;
    const int t    = threadIdx.x;
    const int w    = t >> 6;
    const int lane = t & 63;
    const int quad = lane >> 4;
    const int ln   = lane & 15;

    const int ibase = i0 + w * 16;
    const int lofs  = (quad * 16 + ln) * 8;

    const short8 qfrag = *(const short8*)(qb + (((size_t)b * 256 + (ibase >> 4)) * 512) + lofs);

    f32x4 acc[4][4];                             // [i-tile][c-chunk]
    #pragma unroll
    for (int it = 0; it < 4; ++it)
        #pragma unroll
        for (int cc = 0; cc < 4; ++cc) acc[it][cc] = (f32x4){0.f, 0.f, 0.f, 0.f};
    float accl[4] = {0.f, 0.f, 0.f, 0.f};

    const unsigned short* kbase = kb + (size_t)b * 256 * 512;
    const unsigned short* vbase = vb + (size_t)b * 128 * 8192;

    // ---- prologue: prefetch j0 = 0 fragments ----
    short8 kf[4], vf[4][2];
    #pragma unroll
    for (int jc = 0; jc < 4; ++jc)
        kf[jc] = *(const short8*)(kbase + (size_t)jc * 512 + lofs);
    #pragma unroll
    for (int cc = 0; cc < 4; ++cc) {
        vf[cc][0] = *(const short8*)(vbase + (w * 4 + cc) * 512 + lofs);
        vf[cc][1] = *(const short8*)(vbase + 8192 + (w * 4 + cc) * 512 + lofs);
    }

    int pb = 0;
    for (int j0 = 0; j0 < 4096; j0 += 64, pb ^= 1) {
        // ---- issue next iteration's K/V loads first (wrap at the end) ----
        const int jn = (j0 + 64) & 4095;
        short8 kf_n[4], vf_n[4][2];
        #pragma unroll
        for (int jc = 0; jc < 4; ++jc)
            kf_n[jc] = *(const short8*)(kbase + ((size_t)((jn >> 4) + jc) * 512) + lofs);
        const unsigned short* vt_n = vbase + (size_t)(jn >> 5) * 8192;
        #pragma unroll
        for (int cc = 0; cc < 4; ++cc) {
            vf_n[cc][0] = *(const short8*)(vt_n + (w * 4 + cc) * 512 + lofs);
            vf_n[cc][1] = *(const short8*)(vt_n + 8192 + (w * 4 + cc) * 512 + lofs);
        }
        // ---- S' = Q K'^T with resident K (K pre-scaled by log2e) ----
        f32x4 s[4];
        #pragma unroll
        for (int jc = 0; jc < 4; ++jc)
            s[jc] = __builtin_amdgcn_mfma_f32_16x16x32_bf16(qfrag, kf[jc],
                     (f32x4){0.f, 0.f, 0.f, 0.f}, 0, 0, 0);
        // ---- P = exp2(S'); row sums; write block-shared P (C-layout) ----
        #pragma unroll
        for (int jc = 0; jc < 4; ++jc) {
            #pragma unroll
            for (int r = 0; r < 4; ++r) {
                float p = exp2f(s[jc][r]);
                accl[r] += p;
                shbuf[((size_t)(pb * 64 + w * 16 + quad * 4 + r)) * 72 + jc * 16 + ln] = f2b(p);
            }
        }
        __syncthreads();
        // ---- O += P V with resident V : 32 MFMAs ----
        #pragma unroll
        for (int it = 0; it < 4; ++it) {
            const short8 pf0 = *(const short8*)&shbuf[((size_t)(pb * 64 + it * 16 + ln)) * 72 + quad * 8];
            const short8 pf1 = *(const short8*)&shbuf[((size_t)(pb * 64 + it * 16 + ln)) * 72 + 32 + quad * 8];
            #pragma unroll
            for (int cc = 0; cc < 4; ++cc) {
                acc[it][cc] = __builtin_amdgcn_mfma_f32_16x16x32_bf16(pf0, vf[cc][0], acc[it][cc], 0, 0, 0);
                acc[it][cc] = __builtin_amdgcn_mfma_f32_16x16x32_bf16(pf1, vf[cc][1], acc[it][cc], 0, 0, 0);
            }
        }
        // ---- rotate prefetched fragments ----
        #pragma unroll
        for (int jc = 0; jc < 4; ++jc) kf[jc] = kf_n[jc];
        #pragma unroll
        for (int cc = 0; cc < 4; ++cc) {
            vf[cc][0] = vf_n[cc][0];
            vf[cc][1] = vf_n[cc][1];
        }
    }

    #pragma unroll
    for (int r = 0; r < 4; ++r) {
        float v = accl[r];
        v += __shfl_xor(v, 1, 16);
        v += __shfl_xor(v, 2, 16);
        v += __shfl_xor(v, 4, 16);
        v += __shfl_xor(v, 8, 16);
        if (ln == 0) lred[w * 16 + quad * 4 + r] = v;
    }
    __syncthreads();   // also orders: last P reads before O_n overwrites shbuf

    // ---- epilogue A: normalize O, write bf16 to LDS [i][c] (stride 264) ----
    #pragma unroll
    for (int it = 0; it < 4; ++it) {
        float linv[4];
        #pragma unroll
        for (int r = 0; r < 4; ++r) linv[r] = 1.f / lred[it * 16 + quad * 4 + r];
        #pragma unroll
        for (int cc = 0; cc < 4; ++cc) {
            const int c = w * 64 + cc * 16 + ln;
            #pragma unroll
            for (int r = 0; r < 4; ++r)
                shbuf[((size_t)(it * 16 + quad * 4 + r)) * 264 + c] = f2b(acc[it][cc][r] * linv[r]);
        }
    }
    __syncthreads();

    // ---- epilogue B: out = Wf * O_n + bf, each wave owns o-chunk w*64 ----
    #pragma unroll
    for (int it = 0; it < 4; ++it) {
        short8 af[8];
        #pragma unroll
        for (int kk = 0; kk < 8; ++kk)
            af[kk] = *(const short8*)&shbuf[((size_t)(it * 16 + ln)) * 264 + kk * 32 + quad * 8];
        #pragma unroll
        for (int oq = 0; oq < 4; ++oq) {
            const int o  = w * 64 + oq * 16 + ln;
            const int og = 20 + w * 4 + oq;
            f32x4 pa = {0.f, 0.f, 0.f, 0.f};
            #pragma unroll
            for (int kk = 0; kk < 8; ++kk) {
                short8 bfr = *(const short8*)(wsw + (size_t)(og * 8 + kk) * 512 + lofs);
                pa = __builtin_amdgcn_mfma_f32_16x16x32_bf16(af[kk], bfr, pa, 0, 0, 0);
            }
            const float bias = bfb[o];
            float4 s = {pa[0] + bias, pa[1] + bias, pa[2] + bias, pa[3] + bias};
            *(float4*)(out + (size_t)(b * 256 + o) * 4096 + i0 + it * 16 + quad * 4) = s;
        }
    }
}

// ---------------------------------------------------------------------------
extern "C" void kernel_launch(void* const* d_in, const int* in_sizes, int n_in,
                              void* d_out, int out_size, void* d_ws, size_t ws_size,
                              hipStream_t stream)
{
    const float* x  = (const float*)d_in[0];
    const float* Wq = (const float*)d_in[1];
    const float* bq = (const float*)d_in[2];
    const float* Wk = (const float*)d_in[3];
    const float* bk = (const float*)d_in[4];
    const float* Wv = (const float*)d_in[5];
    const float* bv = (const float*)d_in[6];
    const float* Wf = (const float*)d_in[7];
    const float* bf = (const float*)d_in[8];
    float* out = (float*)d_out;

    // workspace (shorts): qb, kb, vb, wsw
    unsigned short* qb  = (unsigned short*)d_ws;                  // 8*4096*32
    unsigned short* kb  = qb + (size_t)BATCH * NPOS * CQK;
    unsigned short* vb  = kb + (size_t)BATCH * NPOS * CQK;        // 8*256*4096
    unsigned short* wsw = vb + (size_t)BATCH * CCH * NPOS;        // 36*8*512

    prep_w_kernel<<<36, 256, 0, stream>>>(Wq, Wk, Wv, Wf, wsw);
    qkv_kernel<<<dim3(64, 8), 512, 0, stream>>>(x, wsw, bq, bk, bv, qb, kb, vb);
    attn_kernel<<<512, 256, 0, stream>>>(qb, kb, vb, wsw, bf, out);
}

// Round 11
// 199.571 us; speedup vs baseline: 1.0880x; 1.0880x over previous
//
#include <hip/hip_runtime.h>
#include <hip/hip_bf16.h>

// Problem constants
#define BATCH 8
#define CCH   256
#define NPOS  4096
#define CQK   32
#define LOG2E 1.4426950408889634f

// ---------------------------------------------------------------------------
// Fast exp path.  R9 lesson: plain exp2f is libm-correct (edge-case fixup
// code around v_exp_f32) and cost +18 µs vs __expf.  The raw instruction is
// __builtin_amdgcn_exp2f.  Hedge: if the builtin is unavailable, fall back
// to the R2-measured __expf path (K then NOT pre-scaled -> bit-identical R2).
// ---------------------------------------------------------------------------
#if defined(__has_builtin)
#if __has_builtin(__builtin_amdgcn_exp2f)
#define HAVE_EXP2 1
#endif
#endif
#ifndef HAVE_EXP2
#define HAVE_EXP2 0
#endif

#if HAVE_EXP2
#define KSC_W LOG2E                    // pre-scale Wk/bk by log2e at prep
__device__ inline float fast_exp(float x) { return __builtin_amdgcn_exp2f(x); }
#else
#define KSC_W 1.0f
__device__ inline float fast_exp(float x) { return __expf(x); }
#endif

typedef __attribute__((ext_vector_type(8))) short short8;   // 8 bf16 = 4 VGPRs (MFMA A/B frag)
typedef __attribute__((ext_vector_type(4))) float f32x4;    // MFMA C/D frag

__device__ inline unsigned short f2b(float f) {
    __hip_bfloat16 h = __float2bfloat16(f);
    return *reinterpret_cast<unsigned short*>(&h);
}

// ---------------------------------------------------------------------------
// Fragment-block swizzled layouts.  A 512-short block holds one 16x32 MFMA
// operand tile; lane (q=quad, ln) reads short8 at block*512 + (q*16+ln)*8.
//   qb/kb: qk_addr  — [b][n>>4][c>>3][n&15][c&7]           (c < 32)
//   vb:     v_addr  — [b][j>>5][c>>4][(j>>3)&3][c&15][j&7]
//   wsw:    wsw_addr — og-unit = 16 rows x 256 c; og: q=0..1,k=2..3,v=4..19,f=20..35
// ---------------------------------------------------------------------------
__device__ inline size_t qk_addr(int b, int n, int c) {
    return ((((size_t)b * 256 + (n >> 4)) * 4 + (c >> 3)) * 16 + (n & 15)) * 8 + (c & 7);
}
__device__ inline size_t v_addr(int b, int c, int j) {
    return (((((size_t)b * 128 + (j >> 5)) * 16 + (c >> 4)) * 4 + ((j >> 3) & 3)) * 16 + (c & 15)) * 8 + (j & 7);
}
__device__ inline size_t wsw_addr(int og, int c, int ol) {
    return ((size_t)(og * 8 + (c >> 5))) * 512 + (((c >> 3) & 3) * 16 + ol) * 8 + (c & 7);
}

// ---------------------------------------------------------------------------
// Kernel 0: prep_w — weights fp32 -> wsw bf16 fragment layout.
// Wk (og 2..3) scaled by KSC_W (log2e when the exp2 builtin is available).
// ---------------------------------------------------------------------------
__global__ __launch_bounds__(256, 4)
void prep_w_kernel(const float* __restrict__ Wq, const float* __restrict__ Wk,
                   const float* __restrict__ Wv, const float* __restrict__ Wf,
                   unsigned short* __restrict__ wsw)
{
    const int og = blockIdx.x;           // 0..35
    const int t  = threadIdx.x;
    const float* src; int orow; float scl = 1.f;
    if (og < 2)       { src = Wq; orow = og * 16; }
    else if (og < 4)  { src = Wk; orow = (og - 2) * 16; scl = KSC_W; }
    else if (og < 20) { src = Wv; orow = (og - 4) * 16; }
    else              { src = Wf; orow = (og - 20) * 16; }
    #pragma unroll
    for (int e = 0; e < 16; ++e) {
        int idx = t + e * 256;
        int ol = idx >> 8, c = idx & 255;
        wsw[wsw_addr(og, c, ol)] = f2b(src[(orow + ol) * 256 + c] * scl);
    }
}

// ---------------------------------------------------------------------------
// Kernel 1: fused transpose + QKV projection (best-measured structure,
// unchanged; k-side bias scaled by KSC_W to match Wk).
// ---------------------------------------------------------------------------
__global__ __launch_bounds__(512, 2)
void qkv_kernel(const float* __restrict__ x,
                const unsigned short* __restrict__ wsw,
                const float* __restrict__ bq, const float* __restrict__ bk,
                const float* __restrict__ bv,
                unsigned short* __restrict__ qb, unsigned short* __restrict__ kb,
                unsigned short* __restrict__ vb)
{
    __shared__ __align__(16) unsigned short xl[64 * 280];   // [n][c pad 280] = 35840 B

    const int nt   = blockIdx.x;          // 64 position tiles
    const int b    = blockIdx.y;
    const int t    = threadIdx.x;         // 0..511
    const int w    = t >> 6;              // 0..7
    const int lane = t & 63;
    const int q    = lane >> 4;
    const int ln   = lane & 15;
    const int lofs = (q * 16 + ln) * 8;
    const int wq   = w & 3;               // role: 0-1 q, 2-3 k (+ v og chunk)
    const int ith  = w >> 2;              // it-half

    // ---- stage x tile [256c x 64n] -> bf16 LDS transposed [n][c] ----
    {
        const int c  = t & 255;
        const int nb = (t >> 8) * 4;
        const float* xb = x + ((size_t)(b * 256 + c)) * 4096 + nt * 64;
        #pragma unroll
        for (int e = 0; e < 8; ++e) {
            const int n = nb + e * 8;
            float4 v = *(const float4*)(xb + n);
            xl[(n + 0) * 280 + c] = f2b(v.x);
            xl[(n + 1) * 280 + c] = f2b(v.y);
            xl[(n + 2) * 280 + c] = f2b(v.z);
            xl[(n + 3) * 280 + c] = f2b(v.w);
        }
    }
    __syncthreads();

    // ---- q/k weight fragments (og = wq) + bias (k side scaled by KSC_W) ----
    short8 wqk[8];
    #pragma unroll
    for (int kk = 0; kk < 8; ++kk)
        wqk[kk] = *(const short8*)(wsw + (size_t)(wq * 8 + kk) * 512 + lofs);
    const float* bias = (wq < 2) ? bq : bk;
    const float ksc = (wq < 2) ? 1.f : KSC_W;
    const int cb16 = (wq & 1) * 16;
    const float b0 = bias[cb16 + q * 4 + 0] * ksc;
    const float b1 = bias[cb16 + q * 4 + 1] * ksc;
    const float b2 = bias[cb16 + q * 4 + 2] * ksc;
    const float b3 = bias[cb16 + q * 4 + 3] * ksc;
    unsigned short* dst = (wq < 2) ? qb : kb;

    #pragma unroll
    for (int itl = 0; itl < 2; ++itl) {
        const int it = ith * 2 + itl;
        short8 xf[8];
        #pragma unroll
        for (int kk = 0; kk < 8; ++kk)
            xf[kk] = *(const short8*)&xl[(it * 16 + ln) * 280 + kk * 32 + q * 8];

        // ---- q/k: D[o-rows][n-cols] ----
        {
            f32x4 acc = {b0, b1, b2, b3};
            #pragma unroll
            for (int kk = 0; kk < 8; ++kk)
                acc = __builtin_amdgcn_mfma_f32_16x16x32_bf16(wqk[kk], xf[kk], acc, 0, 0, 0);
            ushort4 s = {f2b(acc[0]), f2b(acc[1]), f2b(acc[2]), f2b(acc[3])};
            *(ushort4*)(dst + qk_addr(b, nt * 64 + it * 16 + ln, cb16 + q * 4)) = s;
        }

        // ---- v: D[j-rows][c-cols], o-chunk wq*64 ----
        #pragma unroll
        for (int oq = 0; oq < 4; ++oq) {
            const int c  = wq * 64 + oq * 16 + ln;
            const float bb = bv[c];
            f32x4 acc = {bb, bb, bb, bb};
            const int og = 4 + wq * 4 + oq;
            #pragma unroll
            for (int kk = 0; kk < 8; ++kk) {
                short8 bfr = *(const short8*)(wsw + (size_t)(og * 8 + kk) * 512 + lofs);
                acc = __builtin_amdgcn_mfma_f32_16x16x32_bf16(xf[kk], bfr, acc, 0, 0, 0);
            }
            ushort4 s = {f2b(acc[0]), f2b(acc[1]), f2b(acc[2]), f2b(acc[3])};
            *(ushort4*)(vb + v_addr(b, c, nt * 64 + it * 16 + q * 4)) = s;
        }
    }
}

// ---------------------------------------------------------------------------
// Kernel 2: fused flash attention + output projection — R2's best-measured
// structure (103.4 µs), exp via fast_exp(): __builtin_amdgcn_exp2f with
// pre-scaled K (one v_exp_f32, no v_mul) or __expf fallback (= R2 exactly).
// ---------------------------------------------------------------------------
__global__ __launch_bounds__(256, 2)
void attn_kernel(const unsigned short* __restrict__ qb,
                 const unsigned short* __restrict__ kb,
                 const unsigned short* __restrict__ vb,
                 const unsigned short* __restrict__ wsw,
                 const float* __restrict__ bfb, float* __restrict__ out)
{
    // shbuf aliases: main loop P tiles [2][64][72] (9216 shorts),
    //                epilogue O_n      [64][264]   (16896 shorts)
    __shared__ __align__(16) unsigned short shbuf[64 * 264];
    __shared__ float lred[64];

    const int bid  = blockIdx.x;
    const int b    = bid & 7;                    // XCD swizzle
    const int i0   = (bid >> 3) * 64;
    const int t    = threadIdx.x;
    const int w    = t >> 6;
    const int lane = t & 63;
    const int quad = lane >> 4;
    const int ln   = lane & 15;

    const int ibase = i0 + w * 16;
    const int lofs  = (quad * 16 + ln) * 8;

    const short8 qfrag = *(const short8*)(qb + (((size_t)b * 256 + (ibase >> 4)) * 512) + lofs);

    f32x4 acc[4][4];                             // [i-tile][c-chunk]
    #pragma unroll
    for (int it = 0; it < 4; ++it)
        #pragma unroll
        for (int cc = 0; cc < 4; ++cc) acc[it][cc] = (f32x4){0.f, 0.f, 0.f, 0.f};
    float accl[4] = {0.f, 0.f, 0.f, 0.f};

    const unsigned short* kbase = kb + (size_t)b * 256 * 512;
    const unsigned short* vbase = vb + (size_t)b * 128 * 8192;

    // ---- prologue: prefetch j0 = 0 fragments ----
    short8 kf[4], vf[4][2];
    #pragma unroll
    for (int jc = 0; jc < 4; ++jc)
        kf[jc] = *(const short8*)(kbase + (size_t)jc * 512 + lofs);
    #pragma unroll
    for (int cc = 0; cc < 4; ++cc) {
        vf[cc][0] = *(const short8*)(vbase + (w * 4 + cc) * 512 + lofs);
        vf[cc][1] = *(const short8*)(vbase + 8192 + (w * 4 + cc) * 512 + lofs);
    }

    int pb = 0;
    for (int j0 = 0; j0 < 4096; j0 += 64, pb ^= 1) {
        // ---- issue next iteration's K/V loads first (wrap at the end) ----
        const int jn = (j0 + 64) & 4095;
        short8 kf_n[4], vf_n[4][2];
        #pragma unroll
        for (int jc = 0; jc < 4; ++jc)
            kf_n[jc] = *(const short8*)(kbase + ((size_t)((jn >> 4) + jc) * 512) + lofs);
        const unsigned short* vt_n = vbase + (size_t)(jn >> 5) * 8192;
        #pragma unroll
        for (int cc = 0; cc < 4; ++cc) {
            vf_n[cc][0] = *(const short8*)(vt_n + (w * 4 + cc) * 512 + lofs);
            vf_n[cc][1] = *(const short8*)(vt_n + 8192 + (w * 4 + cc) * 512 + lofs);
        }
        // ---- S = Q K^T with resident K ----
        f32x4 s[4];
        #pragma unroll
        for (int jc = 0; jc < 4; ++jc)
            s[jc] = __builtin_amdgcn_mfma_f32_16x16x32_bf16(qfrag, kf[jc],
                     (f32x4){0.f, 0.f, 0.f, 0.f}, 0, 0, 0);
        // ---- P = exp(S); row sums; write block-shared P (C-layout) ----
        #pragma unroll
        for (int jc = 0; jc < 4; ++jc) {
            #pragma unroll
            for (int r = 0; r < 4; ++r) {
                float p = fast_exp(s[jc][r]);
                accl[r] += p;
                shbuf[((size_t)(pb * 64 + w * 16 + quad * 4 + r)) * 72 + jc * 16 + ln] = f2b(p);
            }
        }
        __syncthreads();
        // ---- O += P V with resident V : 32 MFMAs ----
        #pragma unroll
        for (int it = 0; it < 4; ++it) {
            const short8 pf0 = *(const short8*)&shbuf[((size_t)(pb * 64 + it * 16 + ln)) * 72 + quad * 8];
            const short8 pf1 = *(const short8*)&shbuf[((size_t)(pb * 64 + it * 16 + ln)) * 72 + 32 + quad * 8];
            #pragma unroll
            for (int cc = 0; cc < 4; ++cc) {
                acc[it][cc] = __builtin_amdgcn_mfma_f32_16x16x32_bf16(pf0, vf[cc][0], acc[it][cc], 0, 0, 0);
                acc[it][cc] = __builtin_amdgcn_mfma_f32_16x16x32_bf16(pf1, vf[cc][1], acc[it][cc], 0, 0, 0);
            }
        }
        // ---- rotate prefetched fragments ----
        #pragma unroll
        for (int jc = 0; jc < 4; ++jc) kf[jc] = kf_n[jc];
        #pragma unroll
        for (int cc = 0; cc < 4; ++cc) {
            vf[cc][0] = vf_n[cc][0];
            vf[cc][1] = vf_n[cc][1];
        }
    }

    #pragma unroll
    for (int r = 0; r < 4; ++r) {
        float v = accl[r];
        v += __shfl_xor(v, 1, 16);
        v += __shfl_xor(v, 2, 16);
        v += __shfl_xor(v, 4, 16);
        v += __shfl_xor(v, 8, 16);
        if (ln == 0) lred[w * 16 + quad * 4 + r] = v;
    }
    __syncthreads();   // also orders: last P reads before O_n overwrites shbuf

    // ---- epilogue A: normalize O, write bf16 to LDS [i][c] (stride 264) ----
    #pragma unroll
    for (int it = 0; it < 4; ++it) {
        float linv[4];
        #pragma unroll
        for (int r = 0; r < 4; ++r) linv[r] = 1.f / lred[it * 16 + quad * 4 + r];
        #pragma unroll
        for (int cc = 0; cc < 4; ++cc) {
            const int c = w * 64 + cc * 16 + ln;
            #pragma unroll
            for (int r = 0; r < 4; ++r)
                shbuf[((size_t)(it * 16 + quad * 4 + r)) * 264 + c] = f2b(acc[it][cc][r] * linv[r]);
        }
    }
    __syncthreads();

    // ---- epilogue B: out = Wf * O_n + bf, each wave owns o-chunk w*64 ----
    #pragma unroll
    for (int it = 0; it < 4; ++it) {
        short8 af[8];
        #pragma unroll
        for (int kk = 0; kk < 8; ++kk)
            af[kk] = *(const short8*)&shbuf[((size_t)(it * 16 + ln)) * 264 + kk * 32 + quad * 8];
        #pragma unroll
        for (int oq = 0; oq < 4; ++oq) {
            const int o  = w * 64 + oq * 16 + ln;
            const int og = 20 + w * 4 + oq;
            f32x4 pa = {0.f, 0.f, 0.f, 0.f};
            #pragma unroll
            for (int kk = 0; kk < 8; ++kk) {
                short8 bfr = *(const short8*)(wsw + (size_t)(og * 8 + kk) * 512 + lofs);
                pa = __builtin_amdgcn_mfma_f32_16x16x32_bf16(af[kk], bfr, pa, 0, 0, 0);
            }
            const float bias = bfb[o];
            float4 s = {pa[0] + bias, pa[1] + bias, pa[2] + bias, pa[3] + bias};
            *(float4*)(out + (size_t)(b * 256 + o) * 4096 + i0 + it * 16 + quad * 4) = s;
        }
    }
}

// ---------------------------------------------------------------------------
extern "C" void kernel_launch(void* const* d_in, const int* in_sizes, int n_in,
                              void* d_out, int out_size, void* d_ws, size_t ws_size,
                              hipStream_t stream)
{
    const float* x  = (const float*)d_in[0];
    const float* Wq = (const float*)d_in[1];
    const float* bq = (const float*)d_in[2];
    const float* Wk = (const float*)d_in[3];
    const float* bk = (const float*)d_in[4];
    const float* Wv = (const float*)d_in[5];
    const float* bv = (const float*)d_in[6];
    const float* Wf = (const float*)d_in[7];
    const float* bf = (const float*)d_in[8];
    float* out = (float*)d_out;

    // workspace (shorts): qb, kb, vb, wsw
    unsigned short* qb  = (unsigned short*)d_ws;                  // 8*4096*32
    unsigned short* kb  = qb + (size_t)BATCH * NPOS * CQK;
    unsigned short* vb  = kb + (size_t)BATCH * NPOS * CQK;        // 8*256*4096
    unsigned short* wsw = vb + (size_t)BATCH * CCH * NPOS;        // 36*8*512

    prep_w_kernel<<<36, 256, 0, stream>>>(Wq, Wk, Wv, Wf, wsw);
    qkv_kernel<<<dim3(64, 8), 512, 0, stream>>>(x, wsw, bq, bk, bv, qb, kb, vb);
    attn_kernel<<<512, 256, 0, stream>>>(qb, kb, vb, wsw, bf, out);
}

// Round 12
// 197.249 us; speedup vs baseline: 1.1008x; 1.0118x over previous
//
#include <hip/hip_runtime.h>
#include <hip/hip_bf16.h>

// Problem constants
#define BATCH 8
#define CCH   256
#define NPOS  4096
#define CQK   32
#define LOG2E 1.4426950408889634f

// ---------------------------------------------------------------------------
// Fast exp path (R11-verified: −11 pts VALUBusy vs __expf).
// ---------------------------------------------------------------------------
#if defined(__has_builtin)
#if __has_builtin(__builtin_amdgcn_exp2f)
#define HAVE_EXP2 1
#endif
#endif
#ifndef HAVE_EXP2
#define HAVE_EXP2 0
#endif

#if HAVE_EXP2
#define KSC_W LOG2E                    // pre-scale Wk/bk by log2e at prep
__device__ inline float fast_exp(float x) { return __builtin_amdgcn_exp2f(x); }
#else
#define KSC_W 1.0f
__device__ inline float fast_exp(float x) { return __expf(x); }
#endif

typedef __attribute__((ext_vector_type(8))) short short8;   // 8 bf16 = 4 VGPRs (MFMA A/B frag)
typedef __attribute__((ext_vector_type(4))) float f32x4;    // MFMA C/D frag

__device__ inline unsigned short f2b(float f) {
    __hip_bfloat16 h = __float2bfloat16(f);
    return *reinterpret_cast<unsigned short*>(&h);
}

// ---------------------------------------------------------------------------
// Fragment-block swizzled layouts (unchanged, harness-verified).
// ---------------------------------------------------------------------------
__device__ inline size_t qk_addr(int b, int n, int c) {
    return ((((size_t)b * 256 + (n >> 4)) * 4 + (c >> 3)) * 16 + (n & 15)) * 8 + (c & 7);
}
__device__ inline size_t v_addr(int b, int c, int j) {
    return (((((size_t)b * 128 + (j >> 5)) * 16 + (c >> 4)) * 4 + ((j >> 3) & 3)) * 16 + (c & 15)) * 8 + (j & 7);
}
__device__ inline size_t wsw_addr(int og, int c, int ol) {
    return ((size_t)(og * 8 + (c >> 5))) * 512 + (((c >> 3) & 3) * 16 + ol) * 8 + (c & 7);
}

// ---------------------------------------------------------------------------
// Kernel 0: prep_w (unchanged from R11).
// ---------------------------------------------------------------------------
__global__ __launch_bounds__(256, 4)
void prep_w_kernel(const float* __restrict__ Wq, const float* __restrict__ Wk,
                   const float* __restrict__ Wv, const float* __restrict__ Wf,
                   unsigned short* __restrict__ wsw)
{
    const int og = blockIdx.x;           // 0..35
    const int t  = threadIdx.x;
    const float* src; int orow; float scl = 1.f;
    if (og < 2)       { src = Wq; orow = og * 16; }
    else if (og < 4)  { src = Wk; orow = (og - 2) * 16; scl = KSC_W; }
    else if (og < 20) { src = Wv; orow = (og - 4) * 16; }
    else              { src = Wf; orow = (og - 20) * 16; }
    #pragma unroll
    for (int e = 0; e < 16; ++e) {
        int idx = t + e * 256;
        int ol = idx >> 8, c = idx & 255;
        wsw[wsw_addr(og, c, ol)] = f2b(src[(orow + ol) * 256 + c] * scl);
    }
}

// ---------------------------------------------------------------------------
// Kernel 1: fused transpose + QKV projection (unchanged from R11).
// ---------------------------------------------------------------------------
__global__ __launch_bounds__(512, 2)
void qkv_kernel(const float* __restrict__ x,
                const unsigned short* __restrict__ wsw,
                const float* __restrict__ bq, const float* __restrict__ bk,
                const float* __restrict__ bv,
                unsigned short* __restrict__ qb, unsigned short* __restrict__ kb,
                unsigned short* __restrict__ vb)
{
    __shared__ __align__(16) unsigned short xl[64 * 280];   // [n][c pad 280] = 35840 B

    const int nt   = blockIdx.x;
    const int b    = blockIdx.y;
    const int t    = threadIdx.x;
    const int w    = t >> 6;
    const int lane = t & 63;
    const int q    = lane >> 4;
    const int ln   = lane & 15;
    const int lofs = (q * 16 + ln) * 8;
    const int wq   = w & 3;
    const int ith  = w >> 2;

    {
        const int c  = t & 255;
        const int nb = (t >> 8) * 4;
        const float* xb = x + ((size_t)(b * 256 + c)) * 4096 + nt * 64;
        #pragma unroll
        for (int e = 0; e < 8; ++e) {
            const int n = nb + e * 8;
            float4 v = *(const float4*)(xb + n);
            xl[(n + 0) * 280 + c] = f2b(v.x);
            xl[(n + 1) * 280 + c] = f2b(v.y);
            xl[(n + 2) * 280 + c] = f2b(v.z);
            xl[(n + 3) * 280 + c] = f2b(v.w);
        }
    }
    __syncthreads();

    short8 wqk[8];
    #pragma unroll
    for (int kk = 0; kk < 8; ++kk)
        wqk[kk] = *(const short8*)(wsw + (size_t)(wq * 8 + kk) * 512 + lofs);
    const float* bias = (wq < 2) ? bq : bk;
    const float ksc = (wq < 2) ? 1.f : KSC_W;
    const int cb16 = (wq & 1) * 16;
    const float b0 = bias[cb16 + q * 4 + 0] * ksc;
    const float b1 = bias[cb16 + q * 4 + 1] * ksc;
    const float b2 = bias[cb16 + q * 4 + 2] * ksc;
    const float b3 = bias[cb16 + q * 4 + 3] * ksc;
    unsigned short* dst = (wq < 2) ? qb : kb;

    #pragma unroll
    for (int itl = 0; itl < 2; ++itl) {
        const int it = ith * 2 + itl;
        short8 xf[8];
        #pragma unroll
        for (int kk = 0; kk < 8; ++kk)
            xf[kk] = *(const short8*)&xl[(it * 16 + ln) * 280 + kk * 32 + q * 8];

        {
            f32x4 acc = {b0, b1, b2, b3};
            #pragma unroll
            for (int kk = 0; kk < 8; ++kk)
                acc = __builtin_amdgcn_mfma_f32_16x16x32_bf16(wqk[kk], xf[kk], acc, 0, 0, 0);
            ushort4 s = {f2b(acc[0]), f2b(acc[1]), f2b(acc[2]), f2b(acc[3])};
            *(ushort4*)(dst + qk_addr(b, nt * 64 + it * 16 + ln, cb16 + q * 4)) = s;
        }

        #pragma unroll
        for (int oq = 0; oq < 4; ++oq) {
            const int c  = wq * 64 + oq * 16 + ln;
            const float bb = bv[c];
            f32x4 acc = {bb, bb, bb, bb};
            const int og = 4 + wq * 4 + oq;
            #pragma unroll
            for (int kk = 0; kk < 8; ++kk) {
                short8 bfr = *(const short8*)(wsw + (size_t)(og * 8 + kk) * 512 + lofs);
                acc = __builtin_amdgcn_mfma_f32_16x16x32_bf16(xf[kk], bfr, acc, 0, 0, 0);
            }
            ushort4 s = {f2b(acc[0]), f2b(acc[1]), f2b(acc[2]), f2b(acc[3])};
            *(ushort4*)(vb + v_addr(b, c, nt * 64 + it * 16 + q * 4)) = s;
        }
    }
}

// ---------------------------------------------------------------------------
// Kernel 2: fused flash attention + output projection — R12: 8-wave blocks.
// R11 showed attn is stall-bound (MfmaUtil 34 + VALU 33, ~33% idle) at
// 2 waves/SIMD (grid-capped).  Same algorithm/layouts, but 512-thread blocks:
// waves 0-3 keep the EXACT S/exp/P-write role (rows w*16); all 8 waves split
// PV by c-chunks of 32 -> 16 waves/CU (4/SIMD), 2x occupancy.  V prefetch
// dropped (load at top of iter, used ~500cyc later after S/exp/barrier —
// TLP hides it) to keep VGPR <= 128 for full occupancy.  K prefetch kept.
// ---------------------------------------------------------------------------
__global__ __launch_bounds__(512, 4)
void attn_kernel(const unsigned short* __restrict__ qb,
                 const unsigned short* __restrict__ kb,
                 const unsigned short* __restrict__ vb,
                 const unsigned short* __restrict__ wsw,
                 const float* __restrict__ bfb, float* __restrict__ out)
{
    // shbuf aliases: main loop P tiles [2][64][72] (9216 shorts),
    //                epilogue O_n      [64][264]   (16896 shorts)
    __shared__ __align__(16) unsigned short shbuf[64 * 264];
    __shared__ float lred[64];

    const int bid  = blockIdx.x;
    const int b    = bid & 7;                    // XCD swizzle
    const int i0   = (bid >> 3) * 64;
    const int t    = threadIdx.x;                // 0..511
    const int w    = t >> 6;                     // 0..7
    const int lane = t & 63;
    const int quad = lane >> 4;
    const int ln   = lane & 15;
    const int lofs = (quad * 16 + ln) * 8;

    const unsigned short* kbase = kb + (size_t)b * 256 * 512;
    const unsigned short* vbase = vb + (size_t)b * 128 * 8192;

    // S-role (waves 0-3): rows w*16..w*16+15
    short8 qfrag = {};
    short8 kf[4];
    if (w < 4) {
        qfrag = *(const short8*)(qb + (((size_t)b * 256 + ((i0 + w * 16) >> 4)) * 512) + lofs);
        #pragma unroll
        for (int jc = 0; jc < 4; ++jc)
            kf[jc] = *(const short8*)(kbase + (size_t)jc * 512 + lofs);
    }

    f32x4 acc[4][2];                             // [i-tile][c-chunk of 32: 2 tiles]
    #pragma unroll
    for (int it = 0; it < 4; ++it)
        #pragma unroll
        for (int cc = 0; cc < 2; ++cc) acc[it][cc] = (f32x4){0.f, 0.f, 0.f, 0.f};
    float accl[4] = {0.f, 0.f, 0.f, 0.f};

    int pb = 0;
    for (int j0 = 0; j0 < 4096; j0 += 64, pb ^= 1) {
        // ---- V for THIS iter (single-buffered; used after S/exp/barrier) ----
        short8 vf[2][2];
        const unsigned short* vt = vbase + (size_t)(j0 >> 5) * 8192;
        #pragma unroll
        for (int cc = 0; cc < 2; ++cc) {
            vf[cc][0] = *(const short8*)(vt + (w * 2 + cc) * 512 + lofs);
            vf[cc][1] = *(const short8*)(vt + 8192 + (w * 2 + cc) * 512 + lofs);
        }
        short8 kf_n[4];
        if (w < 4) {
            // ---- prefetch next-iter K ----
            const int jn = (j0 + 64) & 4095;
            #pragma unroll
            for (int jc = 0; jc < 4; ++jc)
                kf_n[jc] = *(const short8*)(kbase + ((size_t)((jn >> 4) + jc) * 512) + lofs);
            // ---- S = Q K^T with resident K ----
            f32x4 s[4];
            #pragma unroll
            for (int jc = 0; jc < 4; ++jc)
                s[jc] = __builtin_amdgcn_mfma_f32_16x16x32_bf16(qfrag, kf[jc],
                         (f32x4){0.f, 0.f, 0.f, 0.f}, 0, 0, 0);
            // ---- P = exp(S); row sums; write block-shared P ----
            #pragma unroll
            for (int jc = 0; jc < 4; ++jc) {
                #pragma unroll
                for (int r = 0; r < 4; ++r) {
                    float p = fast_exp(s[jc][r]);
                    accl[r] += p;
                    shbuf[((size_t)(pb * 64 + w * 16 + quad * 4 + r)) * 72 + jc * 16 + ln] = f2b(p);
                }
            }
        }
        __syncthreads();
        // ---- O += P V : all 8 waves, 16 MFMAs each ----
        #pragma unroll
        for (int it = 0; it < 4; ++it) {
            const short8 pf0 = *(const short8*)&shbuf[((size_t)(pb * 64 + it * 16 + ln)) * 72 + quad * 8];
            const short8 pf1 = *(const short8*)&shbuf[((size_t)(pb * 64 + it * 16 + ln)) * 72 + 32 + quad * 8];
            #pragma unroll
            for (int cc = 0; cc < 2; ++cc) {
                acc[it][cc] = __builtin_amdgcn_mfma_f32_16x16x32_bf16(pf0, vf[cc][0], acc[it][cc], 0, 0, 0);
                acc[it][cc] = __builtin_amdgcn_mfma_f32_16x16x32_bf16(pf1, vf[cc][1], acc[it][cc], 0, 0, 0);
            }
        }
        if (w < 4) {
            #pragma unroll
            for (int jc = 0; jc < 4; ++jc) kf[jc] = kf_n[jc];
        }
    }

    // ---- row sums (waves 0-3 own rows) ----
    if (w < 4) {
        #pragma unroll
        for (int r = 0; r < 4; ++r) {
            float v = accl[r];
            v += __shfl_xor(v, 1, 16);
            v += __shfl_xor(v, 2, 16);
            v += __shfl_xor(v, 4, 16);
            v += __shfl_xor(v, 8, 16);
            if (ln == 0) lred[w * 16 + quad * 4 + r] = v;
        }
    }
    __syncthreads();   // also orders: last P reads before O_n overwrites shbuf

    // ---- epilogue A: normalize O, write bf16 to LDS [i][c] (stride 264) ----
    #pragma unroll
    for (int it = 0; it < 4; ++it) {
        float linv[4];
        #pragma unroll
        for (int r = 0; r < 4; ++r) linv[r] = 1.f / lred[it * 16 + quad * 4 + r];
        #pragma unroll
        for (int cc = 0; cc < 2; ++cc) {
            const int c = w * 32 + cc * 16 + ln;
            #pragma unroll
            for (int r = 0; r < 4; ++r)
                shbuf[((size_t)(it * 16 + quad * 4 + r)) * 264 + c] = f2b(acc[it][cc][r] * linv[r]);
        }
    }
    __syncthreads();

    // ---- epilogue B: out = Wf * O_n + bf, each wave owns o-chunk w*32 ----
    #pragma unroll
    for (int it = 0; it < 4; ++it) {
        short8 af[8];
        #pragma unroll
        for (int kk = 0; kk < 8; ++kk)
            af[kk] = *(const short8*)&shbuf[((size_t)(it * 16 + ln)) * 264 + kk * 32 + quad * 8];
        #pragma unroll
        for (int oq = 0; oq < 2; ++oq) {
            const int o  = w * 32 + oq * 16 + ln;
            const int og = 20 + w * 2 + oq;
            f32x4 pa = {0.f, 0.f, 0.f, 0.f};
            #pragma unroll
            for (int kk = 0; kk < 8; ++kk) {
                short8 bfr = *(const short8*)(wsw + (size_t)(og * 8 + kk) * 512 + lofs);
                pa = __builtin_amdgcn_mfma_f32_16x16x32_bf16(af[kk], bfr, pa, 0, 0, 0);
            }
            const float bias = bfb[o];
            float4 s = {pa[0] + bias, pa[1] + bias, pa[2] + bias, pa[3] + bias};
            *(float4*)(out + (size_t)(b * 256 + o) * 4096 + i0 + it * 16 + quad * 4) = s;
        }
    }
}

// ---------------------------------------------------------------------------
extern "C" void kernel_launch(void* const* d_in, const int* in_sizes, int n_in,
                              void* d_out, int out_size, void* d_ws, size_t ws_size,
                              hipStream_t stream)
{
    const float* x  = (const float*)d_in[0];
    const float* Wq = (const float*)d_in[1];
    const float* bq = (const float*)d_in[2];
    const float* Wk = (const float*)d_in[3];
    const float* bk = (const float*)d_in[4];
    const float* Wv = (const float*)d_in[5];
    const float* bv = (const float*)d_in[6];
    const float* Wf = (const float*)d_in[7];
    const float* bf = (const float*)d_in[8];
    float* out = (float*)d_out;

    // workspace (shorts): qb, kb, vb, wsw
    unsigned short* qb  = (unsigned short*)d_ws;                  // 8*4096*32
    unsigned short* kb  = qb + (size_t)BATCH * NPOS * CQK;
    unsigned short* vb  = kb + (size_t)BATCH * NPOS * CQK;        // 8*256*4096
    unsigned short* wsw = vb + (size_t)BATCH * CCH * NPOS;        // 36*8*512

    prep_w_kernel<<<36, 256, 0, stream>>>(Wq, Wk, Wv, Wf, wsw);
    qkv_kernel<<<dim3(64, 8), 512, 0, stream>>>(x, wsw, bq, bk, bv, qb, kb, vb);
    attn_kernel<<<512, 512, 0, stream>>>(qb, kb, vb, wsw, bf, out);
}